// Round 1
// baseline (45.043 us; speedup 1.0000x reference)
//
#include <hip/hip_runtime.h>
#include <hip/hip_bf16.h>

#define MM 64
#define KTOT 4096
#define NN 11008
#define PACKS 1376   // NN / 8
#define NBLK 172     // NN / BN
#define BN 64
#define KSPLIT 4
#define BKCHUNK 1024 // KTOT / KSPLIT
#define BK 64
#define NSTEP (BKCHUNK / BK)  // 16

typedef float f32x4 __attribute__((ext_vector_type(4)));
typedef short bf16x8 __attribute__((ext_vector_type(8)));

__device__ __forceinline__ unsigned int f2bf(float f) {
    unsigned int b = __float_as_uint(f);
    return (b + 0x7FFFu + ((b >> 16) & 1u)) >> 16;   // RNE to bf16
}
// slot swizzle: spreads both staging writes and frag reads across banks
__device__ __forceinline__ int swz(int row) { return (row ^ (row >> 3)) & 7; }

__global__ __launch_bounds__(256) void init_out(const float* __restrict__ bias,
                                                float* __restrict__ out) {
    int f = blockIdx.x * 256 + threadIdx.x;       // float4 index, 176128 total
    int n = (f * 4) % NN;                          // NN % 4 == 0
    float4 b = *reinterpret_cast<const float4*>(bias + n);
    reinterpret_cast<float4*>(out)[f] = b;
}

__global__ __launch_bounds__(256) void awq_mfma(
    const float* __restrict__ x, const int* __restrict__ qw,
    const int* __restrict__ qz, const float* __restrict__ sc,
    float* __restrict__ out)
{
    __shared__ __attribute__((aligned(16))) unsigned short xs[MM * BK]; // x tile, bf16 [m][k]
    __shared__ __attribute__((aligned(16))) unsigned short wt[BN * BK]; // W^T tile, bf16 [n][k]

    const int tid  = threadIdx.x;
    const int lane = tid & 63;
    const int bn   = blockIdx.x;          // 0..171
    const int bk   = blockIdx.y;          // 0..3 k-split
    const int n0   = bn * BN;
    const int c0   = bn * 8;              // pack-column base (8 int32 per 64 cols)
    const int k00  = bk * BKCHUNK;

    // staging mapping
    const int xrow = tid >> 2;            // 0..63 (x row)
    const int xch  = (tid & 3) * 16;      // k-chunk of 16 floats
    const int cl   = tid & 7;             // pack col offset 0..7
    const int aa   = tid >> 3;            // 0..31 (k pair index; k = 2*aa, 2*aa+1)

    // compute mapping: wave w owns 32x32 quadrant = 2x2 tiles of 16x16
    const int wv  = tid >> 6;
    const int mb  = (wv & 1) * 32;
    const int nb  = (wv >> 1) * 32;
    const int l15 = lane & 15;
    const int l4  = lane >> 4;

    f32x4 acc[2][2] = {};

    for (int st = 0; st < NSTEP; ++st) {
        const int k0 = k00 + st * BK;

        // ---- global loads ----
        const float* xp = x + xrow * KTOT + k0 + xch;
        float4 xv0 = reinterpret_cast<const float4*>(xp)[0];
        float4 xv1 = reinterpret_cast<const float4*>(xp)[1];
        float4 xv2 = reinterpret_cast<const float4*>(xp)[2];
        float4 xv3 = reinterpret_cast<const float4*>(xp)[3];

        const int g  = k0 >> 7;           // group index (BK=64 divides GROUP_SIZE=128)
        const int q0 = qw[(k0 + 2 * aa) * PACKS + c0 + cl];
        const int q1 = qw[(k0 + 2 * aa + 1) * PACKS + c0 + cl];
        const int zz = qz[g * PACKS + c0 + cl];
        const float4 s0v = *reinterpret_cast<const float4*>(sc + g * NN + n0 + cl * 8);
        const float4 s1v = *reinterpret_cast<const float4*>(sc + g * NN + n0 + cl * 8 + 4);

        // ---- dequant in registers (AWQ nibble order: shift = (j>>1)*4 + (j&1)*16) ----
        const float sj[8] = { s0v.x, s0v.y, s0v.z, s0v.w, s1v.x, s1v.y, s1v.z, s1v.w };
        unsigned int pair[8];
        #pragma unroll
        for (int j = 0; j < 8; ++j) {
            const int sh = ((j >> 1) << 2) + ((j & 1) << 4);
            const int zj = (zz >> sh) & 0xF;
            const float nzs = -(float)zj * sj[j];
            const float w0 = fmaf((float)((q0 >> sh) & 0xF), sj[j], nzs);
            const float w1 = fmaf((float)((q1 >> sh) & 0xF), sj[j], nzs);
            pair[j] = f2bf(w0) | (f2bf(w1) << 16);   // low = k even, high = k odd
        }

        const float xf[16] = { xv0.x, xv0.y, xv0.z, xv0.w, xv1.x, xv1.y, xv1.z, xv1.w,
                               xv2.x, xv2.y, xv2.z, xv2.w, xv3.x, xv3.y, xv3.z, xv3.w };
        unsigned int xb[8];
        #pragma unroll
        for (int i = 0; i < 8; ++i)
            xb[i] = f2bf(xf[2 * i]) | (f2bf(xf[2 * i + 1]) << 16);

        __syncthreads();   // previous iteration's compute done reading LDS

        // ---- LDS writes ----
        {
            const int sr = swz(xrow);
            const int slot0 = xch >> 3;   // 2*(tid&3)
            uint4 u0 = make_uint4(xb[0], xb[1], xb[2], xb[3]);
            uint4 u1 = make_uint4(xb[4], xb[5], xb[6], xb[7]);
            *reinterpret_cast<uint4*>(&xs[xrow * 64 + (((slot0    ) ^ sr) << 3)]) = u0;
            *reinterpret_cast<uint4*>(&xs[xrow * 64 + (((slot0 + 1) ^ sr) << 3)]) = u1;
        }
        #pragma unroll
        for (int j = 0; j < 8; ++j) {
            const int row = cl * 8 + j;
            const int col = 2 * aa;
            const int idx = row * 64 + (((col >> 3) ^ swz(row)) << 3) + (col & 7);
            *reinterpret_cast<unsigned int*>(&wt[idx]) = pair[j];
        }

        __syncthreads();

        // ---- MFMA ----
        #pragma unroll
        for (int kk = 0; kk < 2; ++kk) {
            bf16x8 af[2], bf[2];
            #pragma unroll
            for (int mt = 0; mt < 2; ++mt) {
                const int row = mb + mt * 16 + l15;
                const int slot = kk * 4 + l4;
                af[mt] = *reinterpret_cast<const bf16x8*>(&xs[row * 64 + ((slot ^ swz(row)) << 3)]);
            }
            #pragma unroll
            for (int nt = 0; nt < 2; ++nt) {
                const int row = nb + nt * 16 + l15;
                const int slot = kk * 4 + l4;
                bf[nt] = *reinterpret_cast<const bf16x8*>(&wt[row * 64 + ((slot ^ swz(row)) << 3)]);
            }
            #pragma unroll
            for (int mt = 0; mt < 2; ++mt)
                #pragma unroll
                for (int nt = 0; nt < 2; ++nt)
                    acc[mt][nt] = __builtin_amdgcn_mfma_f32_16x16x32_bf16(
                        af[mt], bf[nt], acc[mt][nt], 0, 0, 0);
        }
    }

    // ---- epilogue: atomic accumulate partials (C/D: col=lane&15, row=(lane>>4)*4+r) ----
    #pragma unroll
    for (int mt = 0; mt < 2; ++mt)
        #pragma unroll
        for (int nt = 0; nt < 2; ++nt) {
            const int r0 = mb + mt * 16 + l4 * 4;
            const int cc = n0 + nb + nt * 16 + l15;
            #pragma unroll
            for (int r = 0; r < 4; ++r)
                atomicAdd(&out[(r0 + r) * NN + cc], acc[mt][nt][r]);
        }
}

extern "C" void kernel_launch(void* const* d_in, const int* in_sizes, int n_in,
                              void* d_out, int out_size, void* d_ws, size_t ws_size,
                              hipStream_t stream) {
    const float* x    = (const float*)d_in[0];
    const int*   qw   = (const int*)d_in[1];
    const int*   qz   = (const int*)d_in[2];
    const float* sc   = (const float*)d_in[3];
    const float* bias = (const float*)d_in[4];
    float* out = (float*)d_out;

    init_out<<<dim3((MM * NN / 4) / 256), 256, 0, stream>>>(bias, out);
    awq_mfma<<<dim3(NBLK, KSPLIT), 256, 0, stream>>>(x, qw, qz, sc, out);
}